// Round 7
// baseline (429.667 us; speedup 1.0000x reference)
//
#include <hip/hip_runtime.h>
#include <hip/hip_bf16.h>

#define NB 128
#define NS 1024
#define NE 256
#define NR 64
#define NO 1024
#define NK (NE*NR)   // 16384

typedef __attribute__((ext_vector_type(8))) short short8;          // MFMA A/B frag (8 bf16)
typedef __attribute__((ext_vector_type(4))) float float4v;         // MFMA C/D frag
typedef __attribute__((ext_vector_type(4))) unsigned short ushort4v;
typedef __attribute__((ext_vector_type(8))) unsigned short ushort8v;

static __device__ inline unsigned short f2bf(float x) {
    union { float f; unsigned u; } v; v.f = x;
    unsigned r = v.u + 0x7fffu + ((v.u >> 16) & 1u);   // RNE
    return (unsigned short)(r >> 16);
}
static __device__ inline float bf2f(unsigned short h) {
    union { unsigned u; float f; } v; v.u = ((unsigned)h) << 16;
    return v.f;
}
// hardware RNE pair-convert; compiler fuses to v_cvt_pk_bf16_f32
static __device__ inline unsigned pk(float lo, float hi) {
    union { __hip_bfloat162 h2; unsigned u; } v;
    v.h2.x = __float2bfloat16(lo);
    v.h2.y = __float2bfloat16(hi);
    return v.u;
}

// ---------------------------------------------------------------------------
// k1 (round-5 structure, MEASUREMENT reps loop added):
// parts[ch][b][e][r] = sum_{s-pairs p == ch (mod 4), s<len} F[b,s,e]*R[b,s,r]
// LDS-free per-wave 32e x 64r tile, fragments straight from global.
// reps: opaque runtime repeat (idempotent; acc re-zeroed, epilogue re-stored)
// so the dispatch is long enough to appear in rocprof top-5 with counters.
// ---------------------------------------------------------------------------
#define NCH 4

__global__ __launch_bounds__(512, 4) void k1_mfma(
    const float* __restrict__ fillers, const float* __restrict__ roles,
    const int* __restrict__ lengths, unsigned short* __restrict__ parts,
    int reps)
{
    const int bid = blockIdx.x;
    const int b   = bid >> 2;
    const int ch  = bid & 3;
    const int len = lengths[b];
    const int tid = threadIdx.x;

    const int lane = tid & 63;
    const int wid  = tid >> 6;      // 0..7 : e-tile of 32
    const int lrow = lane & 15;
    const int lgrp = lane >> 4;     // 0..3 : k-group

    const int e0 = wid * 32;

    const int P      = (len + 1) >> 1;
    const int count  = (P > ch) ? ((P - ch + 3) >> 2) : 0;
    const int nsteps = (count + 15) >> 4;    // <= 8

    const float* fb = fillers + (size_t)b * NS * NE;
    const float* rb = roles   + (size_t)b * NS * NR;
    unsigned short* pp = parts + (size_t)(ch * NB + b) * NK;

    for (int rep = 0; rep < reps; ++rep) {

        float4v acc[2][4];   // [mf (16e)][nf (16r)]
        #pragma unroll
        for (int i = 0; i < 2; ++i)
            #pragma unroll
            for (int j = 0; j < 4; ++j)
                acc[i][j] = (float4v){0.f, 0.f, 0.f, 0.f};

        for (int t = 0; t < nsteps; ++t) {
            const int sbase = 128 * t + 32 * lgrp + 2 * ch;
            const int shi   = 128 * t + 121 + 2 * ch;

            float a0[8], a1[8], b0[8], b1[8], b2[8], b3[8];
            #pragma unroll
            for (int j = 0; j < 8; ++j) {
                const int s = sbase + ((j >> 1) << 3) + (j & 1);
                const float* fr = fb + (size_t)s * NE;
                const float* rr = rb + (size_t)s * NR;
                a0[j] = fr[e0 + lrow];
                a1[j] = fr[e0 + 16 + lrow];
                b0[j] = rr[lrow];
                b1[j] = rr[16 + lrow];
                b2[j] = rr[32 + lrow];
                b3[j] = rr[48 + lrow];
            }

            if (shi >= len) {   // boundary step only (wave-uniform branch)
                #pragma unroll
                for (int j = 0; j < 8; ++j) {
                    const int s = sbase + ((j >> 1) << 3) + (j & 1);
                    const bool v = (s < len);
                    a0[j] = v ? a0[j] : 0.f;  a1[j] = v ? a1[j] : 0.f;
                    b0[j] = v ? b0[j] : 0.f;  b1[j] = v ? b1[j] : 0.f;
                    b2[j] = v ? b2[j] : 0.f;  b3[j] = v ? b3[j] : 0.f;
                }
            }

            union { unsigned u[4]; short8 s8; } af[2], bf[4];
            #pragma unroll
            for (int jj = 0; jj < 4; ++jj) {
                af[0].u[jj] = pk(a0[2*jj], a0[2*jj+1]);
                af[1].u[jj] = pk(a1[2*jj], a1[2*jj+1]);
                bf[0].u[jj] = pk(b0[2*jj], b0[2*jj+1]);
                bf[1].u[jj] = pk(b1[2*jj], b1[2*jj+1]);
                bf[2].u[jj] = pk(b2[2*jj], b2[2*jj+1]);
                bf[3].u[jj] = pk(b3[2*jj], b3[2*jj+1]);
            }

            #pragma unroll
            for (int mf = 0; mf < 2; ++mf)
                #pragma unroll
                for (int nf = 0; nf < 4; ++nf)
                    acc[mf][nf] = __builtin_amdgcn_mfma_f32_16x16x32_bf16(
                        af[mf].s8, bf[nf].s8, acc[mf][nf], 0, 0, 0);
        }

        // epilogue: C/D layout col=lane&15 (r), row=(lane>>4)*4+reg (e)
        #pragma unroll
        for (int mf = 0; mf < 2; ++mf) {
            #pragma unroll
            for (int nf = 0; nf < 4; ++nf) {
                const int r = nf * 16 + lrow;
                #pragma unroll
                for (int reg = 0; reg < 4; ++reg) {
                    const int e = e0 + mf * 16 + lgrp * 4 + reg;
                    pp[(size_t)e * NR + r] = f2bf(acc[mf][nf][reg]);
                }
            }
        }
    }
}

// ---------------------------------------------------------------------------
// k1b: tensor[i] = bf16( sum_ch parts[ch][i] )
// ---------------------------------------------------------------------------
__global__ __launch_bounds__(256) void k1b_reduce(
    const unsigned short* __restrict__ parts, unsigned short* __restrict__ tensor)
{
    const size_t i = ((size_t)blockIdx.x * 256 + threadIdx.x) * 8;
    float s[8] = {0.f,0.f,0.f,0.f,0.f,0.f,0.f,0.f};
    #pragma unroll
    for (int ch = 0; ch < NCH; ++ch) {
        ushort8v v = *(const ushort8v*)(parts + (size_t)ch * NB * NK + i);
        #pragma unroll
        for (int j = 0; j < 8; ++j)
            s[j] += bf2f(v[j]);
    }
    ushort8v o;
    #pragma unroll
    for (int j = 0; j < 8; ++j)
        o[j] = f2bf(s[j]);
    *(ushort8v*)(tensor + i) = o;
}

// ---------------------------------------------------------------------------
// k2: part[kz][b][o] = sum_{k in chunk kz} T[b][k] * W[o][k]
// BM = 128 (= NB, W read once), BN = 64, BK = 128, KSPLIT = 32.
// reps: opaque runtime repeat for measurement (idempotent).
// ---------------------------------------------------------------------------
#define BN2 64
#define BK2 128
#define KSPLIT 32
#define KC2 (NK/KSPLIT)   // 512

__global__ __launch_bounds__(512) void k2_mfma(
    const unsigned short* __restrict__ A,   // tensor bf16 [NB][NK]
    const float* __restrict__ W,            // [NO][NK]
    float* __restrict__ part,               // [KSPLIT][NB][NO]
    int reps)
{
    __shared__ unsigned short As[128 * BK2];  // 32 KB, XOR-swizzled 256B rows
    __shared__ unsigned short Bs[BN2 * BK2];  // 16 KB

    const int o0   = blockIdx.x * BN2;
    const int kz   = blockIdx.y;
    const int tid  = threadIdx.x;
    const int lane = tid & 63;
    const int wid  = tid >> 6;
    const int wm   = wid >> 1;   // 0..3
    const int wn   = wid & 1;    // 0..1
    const int lrow = lane & 15;
    const int lgrp = lane >> 4;

    for (int rep = 0; rep < reps; ++rep) {

        float4v acc[2][2];
        #pragma unroll
        for (int i = 0; i < 2; ++i)
            #pragma unroll
            for (int j = 0; j < 2; ++j)
                acc[i][j] = (float4v){0.f, 0.f, 0.f, 0.f};

        for (int step = 0; step < KC2 / BK2; ++step) {   // 4
            const int kb = kz * KC2 + step * BK2;

            ushort8v av[4];
            #pragma unroll
            for (int i = 0; i < 4; ++i) {
                const int c = tid + 512 * i;           // 0..2047
                const int r = c >> 4, c16 = c & 15;    // r 0..127
                av[i] = *(const ushort8v*)(A + (size_t)r * NK + kb + c16 * 8);
            }
            float4 wv[4];
            #pragma unroll
            for (int i = 0; i < 4; ++i) {
                const int c = tid + 512 * i;
                const int r = c >> 5, c4 = c & 31;     // r 0..63
                wv[i] = *(const float4*)(W + (size_t)(o0 + r) * NK + kb + c4 * 4);
            }

            __syncthreads();

            #pragma unroll
            for (int i = 0; i < 4; ++i) {
                const int c = tid + 512 * i;
                const int r = c >> 4, c16 = c & 15;
                const int byte = (r * 256 + c16 * 16) ^ ((r & 7) << 4);
                *(ushort8v*)((char*)As + byte) = av[i];
            }
            #pragma unroll
            for (int i = 0; i < 4; ++i) {
                const int c = tid + 512 * i;
                const int r = c >> 5, c4 = c & 31;
                ushort4v bv = { f2bf(wv[i].x), f2bf(wv[i].y), f2bf(wv[i].z), f2bf(wv[i].w) };
                const int byte = (r * 256 + c4 * 8) ^ ((r & 7) << 4);
                *(ushort4v*)((char*)Bs + byte) = bv;
            }

            __syncthreads();

            #pragma unroll
            for (int kk = 0; kk < BK2; kk += 32) {
                short8 af[2], bf[2];
                #pragma unroll
                for (int mf = 0; mf < 2; ++mf) {
                    const int r = wm * 32 + mf * 16 + lrow;
                    const int byte = (r * 256 + (kk + lgrp * 8) * 2) ^ ((r & 7) << 4);
                    af[mf] = *(const short8*)((const char*)As + byte);
                }
                #pragma unroll
                for (int nf = 0; nf < 2; ++nf) {
                    const int r = wn * 32 + nf * 16 + lrow;
                    const int byte = (r * 256 + (kk + lgrp * 8) * 2) ^ ((r & 7) << 4);
                    bf[nf] = *(const short8*)((const char*)Bs + byte);
                }
                #pragma unroll
                for (int mf = 0; mf < 2; ++mf)
                    #pragma unroll
                    for (int nf = 0; nf < 2; ++nf)
                        acc[mf][nf] = __builtin_amdgcn_mfma_f32_16x16x32_bf16(
                            af[mf], bf[nf], acc[mf][nf], 0, 0, 0);
            }

            __syncthreads();   // reps>1: protect LDS before next rep/step overwrite
        }

        float* pbase = part + (size_t)kz * NB * NO;
        #pragma unroll
        for (int mf = 0; mf < 2; ++mf) {
            #pragma unroll
            for (int nf = 0; nf < 2; ++nf) {
                const int o = o0 + wn * 32 + nf * 16 + lrow;
                #pragma unroll
                for (int reg = 0; reg < 4; ++reg) {
                    const int m = wm * 32 + mf * 16 + lgrp * 4 + reg;
                    pbase[(size_t)m * NO + o] = acc[mf][nf][reg];
                }
            }
        }
    }
}

// ---------------------------------------------------------------------------
// k3: out[b][o] = bias[o] + sum_z part[z][b][o]
// ---------------------------------------------------------------------------
__global__ __launch_bounds__(256) void k3_reduce(
    const float* __restrict__ part, const float* __restrict__ bias,
    float* __restrict__ out)
{
    const int i = (blockIdx.x * 256 + threadIdx.x) * 4;
    float4 v = *(const float4*)(bias + (i & (NO - 1)));
    #pragma unroll
    for (int z = 0; z < KSPLIT; ++z) {
        float4 p = *(const float4*)(part + (size_t)z * NB * NO + i);
        v.x += p.x; v.y += p.y; v.z += p.z; v.w += p.w;
    }
    *(float4*)(out + i) = v;
}

extern "C" void kernel_launch(void* const* d_in, const int* in_sizes, int n_in,
                              void* d_out, int out_size, void* d_ws, size_t ws_size,
                              hipStream_t stream)
{
    const float* fillers = (const float*)d_in[0];
    const float* roles   = (const float*)d_in[1];
    const int*   lengths = (const int*)d_in[2];
    const float* W       = (const float*)d_in[3];
    const float* bias    = (const float*)d_in[4];
    float* out = (float*)d_out;

    // ws: [tensor bf16 4.19MB][parts bf16 4x4.19=16.8MB == overlaid part f32 16.8MB]
    unsigned short* tensor = (unsigned short*)d_ws;
    unsigned short* parts  = tensor + (size_t)NB * NK;   // k1 out, k1b in
    float*          part   = (float*)parts;              // k2 out, k3 in (disjoint lifetime)

    // MEASUREMENT ROUND: reps inflate k1/k2 dispatch durations past the
    // harness's 75us fillBuffer dispatches so they appear in rocprof top-5
    // with full counters. Idempotent -> correctness unchanged.
    k1_mfma<<<NB * NCH, 512, 0, stream>>>(fillers, roles, lengths, parts, 8);
    k1b_reduce<<<(NB * NK / 8) / 256, 256, 0, stream>>>(parts, tensor);
    dim3 g2(NO / BN2, KSPLIT);   // (16, 32)
    k2_mfma<<<g2, 512, 0, stream>>>(tensor, W, part, 16);
    k3_reduce<<<(NB * NO) / 1024, 256, 0, stream>>>(part, bias, out);
}